// Round 2
// baseline (98.303 us; speedup 1.0000x reference)
//
#include <hip/hip_runtime.h>

typedef _Float16 f16;
typedef _Float16 f16x8 __attribute__((ext_vector_type(8)));
typedef _Float16 f16x4 __attribute__((ext_vector_type(4)));
typedef float f32x4 __attribute__((ext_vector_type(4)));

#define MFMA16(a,b,c) __builtin_amdgcn_mfma_f32_16x16x32_f16((a),(b),(c),0,0,0)

__device__ __forceinline__ float sigm(float x){ return 1.0f/(1.0f+__expf(-x)); }
__device__ __forceinline__ float tanhf_(float x){ return 1.0f - 2.0f/(1.0f+__expf(2.0f*x)); }

// ---- K1: Ac[b,i,j] = (sum_d adj[b,i,j,1+d]) - 2  (fp16), rs32[b,i] = exact fp32 rowsum ----
__global__ __launch_bounds__(256) void k_buildA(const float* __restrict__ adj,
                                                f16* __restrict__ Ag,
                                                float* __restrict__ rsG){
    const long long ntask = 2097152LL; // 512*128*128/4
    long long t = (long long)blockIdx.x*256 + threadIdx.x;
    const long long stride = (long long)gridDim.x*256;
    for (; t < ntask; t += stride){
        const float4* p = (const float4*)(adj + t*20);
        float4 a = p[0], b4 = p[1], c4 = p[2], d4 = p[3], e4 = p[4];
        float s0 = a.y  + a.z  + a.w  + b4.x;
        float s1 = b4.z + b4.w + c4.x + c4.y;
        float s2 = c4.w + d4.x + d4.y + d4.z;
        float s3 = e4.x + e4.y + e4.z + e4.w;
        f16x4 o; o[0]=(f16)(s0-2.0f); o[1]=(f16)(s1-2.0f); o[2]=(f16)(s2-2.0f); o[3]=(f16)(s3-2.0f);
        *(f16x4*)(Ag + t*4) = o;
        // exact fp32 rowsum: 32 consecutive threads own one row (aligned groups)
        float v = s0+s1+s2+s3;
        v += __shfl_xor(v, 1, 64); v += __shfl_xor(v, 2, 64);
        v += __shfl_xor(v, 4, 64); v += __shfl_xor(v, 8, 64);
        v += __shfl_xor(v,16, 64);
        if ((threadIdx.x & 31) == 0) rsG[t>>5] = v;
    }
}

// ---- K2: whole per-batch chain in LDS ----
#define S128 136
#define S68  68
#define S72  72

__global__ __launch_bounds__(512,2) void k_main(
    const f16*  __restrict__ Ag, const float* __restrict__ rsG,
    const float* __restrict__ node_g,
    const float* __restrict__ W1,  const float* __restrict__ b1,
    const float* __restrict__ W2,  const float* __restrict__ b2,
    const float* __restrict__ Ws,  const float* __restrict__ bs,
    const float* __restrict__ Wt,  const float* __restrict__ bt,
    const float* __restrict__ Wl1, const float* __restrict__ bl1,
    const float* __restrict__ Wl2, const float* __restrict__ bl2,
    const float* __restrict__ Wo,  const float* __restrict__ bo,
    float* __restrict__ out)
{
    __shared__ __align__(16) char smem[136960];
    f16*   Alds  = (f16*)(smem);               // [128][136]  Ac = A-2 (fp16)
    f16*   h1B   = (f16*)(smem+34816);         // [128][136]  h1^T [c][n]
    f16*   W2B   = (f16*)(smem+34816);         // [64][136]   (after G1, aliases h1B)
    f16*   resid = (f16*)(smem+34816);         // [128][72]   resid'=Ac@d2+d2 (after G2)
    f16*   h_d   = (f16*)(smem+69632);         // [128][136]  h - mean_j(h), [j][c]
    f16*   WsB   = (f16*)(smem+69632);         // [128][68]   (after G2, aliases h_d)
    f16*   WtB   = (f16*)(smem+87040);         // [128][68]
    f16*   d2B   = (f16*)(smem+104448);        // [64][136]   h2 - c, B-layout [n2][j]
    float* node_l= (float*)(smem+121856);      // [640]
    float* W1L   = (float*)(smem+124416);      // [640]
    float* Wsnd  = (float*)(smem+126976);      // [640] Ws rows 64..68
    float* Wtnd  = (float*)(smem+129536);      // [640]
    float* b1L   = (float*)(smem+132096);      // [128]
    float* sum1  = (float*)(smem+132608);      // [128] sum_n h1f32[n][c]
    float* m_h   = (float*)(smem+133120);      // [128]
    float* rsL   = (float*)(smem+133632);      // [128] exact rowsum(A32)
    float* c_ac  = (float*)(smem+134144);      // [64]
    float* cw    = (float*)(smem+134400);      // [128] c@Ws fp32
    float* ctw   = (float*)(smem+134912);      // [128]
    float* g_ac  = (float*)(smem+135424);      // [128]
    float* r1_2  = (float*)(smem+135936);      // [64]  m_h@W2+b2 fp32
    float* t1l   = (float*)(smem+136192);      // [128]
    float* t2l   = (float*)(smem+136704);      // [64]

    const int bidx = blockIdx.x;
    const int tid  = threadIdx.x;
    const int w    = tid>>6, lane = tid&63;
    const int l15  = lane&15, l4 = lane>>4;
    const int irow = w*16 + l15;         // A-operand row for this wave
    const int rb   = w*16 + l4*4;        // C/D row base

    // ---- phase 0: zero + stage (no cross-thread reads yet) ----
    if (tid<128){ m_h[tid]=0.f; g_ac[tid]=0.f; sum1[tid]=0.f;
                  b1L[tid]=b1[tid]; rsL[tid]=rsG[bidx*128+tid]; }
    if (tid<64)  c_ac[tid]=0.f;
    for (int i=tid;i<640;i+=512){
        node_l[i] = node_g[bidx*640+i];
        W1L[i]    = W1[i];
        Wsnd[i]   = Ws[64*128+i];
        Wtnd[i]   = Wt[64*128+i];
    }
    { // stage Ac (fp16, 16B chunks)
        const uint4* src = (const uint4*)(Ag + (long long)bidx*16384);
        #pragma unroll
        for (int it=0; it<4; ++it){
            int idx = it*512 + tid;
            uint4 v = src[idx];
            int i = idx>>4, jc = (idx&15)*8;
            *(uint4*)&Alds[i*S128 + jc] = v;
        }
    }
    __syncthreads();

    { // h1 = node@W1 + b1 (fp32), stored fp16 B-layout [c][n]; fp32 column sums
        int c = tid>>2, nq = (tid&3)*32;
        float w1v[5]; float bb = b1L[c];
        #pragma unroll
        for (int m=0;m<5;++m) w1v[m] = W1L[m*128+c];
        float part = 0.f;
        for (int n=nq; n<nq+32; ++n){
            float a = bb;
            #pragma unroll
            for (int m=0;m<5;++m) a += node_l[n*5+m]*w1v[m];
            h1B[c*S128+n] = (f16)a;
            part += a;
        }
        atomicAdd(&sum1[c], part);
    }
    __syncthreads();

    // ---- G1: h = A@h1 + h1 = Ac@h1 + 2*sum1[c] + h1  (init in exact fp32) ----
    f32x4 acc[8];
    #pragma unroll
    for (int ct=0;ct<8;++ct){
        int c = ct*16+l15;
        float s2c = 2.0f*sum1[c], bb = b1L[c];
        #pragma unroll
        for (int r=0;r<4;++r){
            int n = rb+r;
            float a = bb;
            #pragma unroll
            for (int m=0;m<5;++m) a += node_l[n*5+m]*W1L[m*128+c];
            acc[ct][r] = a + s2c;
        }
    }
    #pragma unroll
    for (int kk=0;kk<4;++kk){
        int ko = kk*32 + l4*8;
        f16x8 af = *(const f16x8*)&Alds[irow*S128 + ko];
        #pragma unroll
        for (int ct=0;ct<8;++ct){
            f16x8 bf = *(const f16x8*)&h1B[(ct*16+l15)*S128 + ko];
            acc[ct] = MFMA16(af, bf, acc[ct]);
        }
    }
    // column means of h (exact mean of OUR h)
    #pragma unroll
    for (int ct=0;ct<8;++ct){
        float v = acc[ct][0]+acc[ct][1]+acc[ct][2]+acc[ct][3];
        v += __shfl_xor(v,16,64); v += __shfl_xor(v,32,64);
        if (lane<16) atomicAdd(&m_h[ct*16+lane], v);
    }
    __syncthreads();
    if (tid<128) m_h[tid] *= (1.0f/128.0f);
    { // stage W2^T -> fp16 (overwrites dead h1B)
        int n2 = tid>>3, c0 = (tid&7)*16;
        #pragma unroll
        for (int cc=0; cc<16; ++cc)
            W2B[n2*S128 + c0+cc] = (f16)W2[(c0+cc)*64 + n2];
    }
    __syncthreads();
    #pragma unroll
    for (int ct=0;ct<8;++ct){ // h_d = h - mean (A-layout [j][c])
        int c = ct*16+l15; float mh = m_h[c];
        #pragma unroll
        for (int r=0;r<4;++r) h_d[(rb+r)*S128 + c] = (f16)(acc[ct][r]-mh);
    }
    if (tid<64){ // rank-1: mean_h @ W2 + b2 in fp32
        float s = b2[tid];
        for (int c=0;c<128;++c) s += m_h[c]*W2[c*64+tid];
        r1_2[tid] = s;
    }
    __syncthreads();

    // ---- G2: h2 = h_d@W2 + (mean_h@W2+b2) ----
    f32x4 acc2[4];
    #pragma unroll
    for (int ct=0;ct<4;++ct){
        float rv = r1_2[ct*16+l15];
        acc2[ct][0]=rv; acc2[ct][1]=rv; acc2[ct][2]=rv; acc2[ct][3]=rv;
    }
    #pragma unroll
    for (int kk=0;kk<4;++kk){
        int ko = kk*32 + l4*8;
        f16x8 af = *(const f16x8*)&h_d[irow*S128 + ko];
        #pragma unroll
        for (int ct=0;ct<4;++ct){
            f16x8 bf = *(const f16x8*)&W2B[(ct*16+l15)*S128 + ko];
            acc2[ct] = MFMA16(af, bf, acc2[ct]);
        }
    }
    #pragma unroll
    for (int ct=0;ct<4;++ct){
        float v = acc2[ct][0]+acc2[ct][1]+acc2[ct][2]+acc2[ct][3];
        v += __shfl_xor(v,16,64); v += __shfl_xor(v,32,64);
        if (lane<16) atomicAdd(&c_ac[ct*16+lane], v);
    }
    __syncthreads();
    if (tid<64) c_ac[tid] *= (1.0f/128.0f);
    __syncthreads();
    #pragma unroll
    for (int ct=0;ct<4;++ct){ // d2 = h2 - c, B-layout [n2][j]
        int n2 = ct*16+l15; float cv = c_ac[n2];
        f16x4 pk;
        #pragma unroll
        for (int r=0;r<4;++r) pk[r] = (f16)(acc2[ct][r]-cv);
        *(f16x4*)&d2B[n2*S128 + rb] = pk;
    }
    if (tid<256){ // cw/ctw = c @ Ws/Wt (fp32 exact rank-1 path)
        int aux = tid&127; const float* Wx = (tid<128)? Ws : Wt;
        float s=0.f;
        for (int n2=0;n2<64;++n2) s += c_ac[n2]*Wx[n2*128+aux];
        ((tid<128)? cw : ctw)[aux] = s;
    }
    { // stage Ws^T/Wt^T rows 0..63 -> fp16 (overwrites dead h_d)
        int aux = tid>>2, q = tid&3;
        #pragma unroll
        for (int k=0;k<16;++k){
            int n2 = q*16+k;
            WsB[aux*S68+n2] = (f16)Ws[n2*128+aux];
            WtB[aux*S68+n2] = (f16)Wt[n2*128+aux];
        }
    }
    __syncthreads();

    // ---- G3: resid' = Ac@d2 + d2   (hb = resid' + (rs+1)*c; sum_j d2 = 0 exactly) ----
    f32x4 acc3[4];
    #pragma unroll
    for (int ct=0;ct<4;++ct){
        int n2 = ct*16+l15;
        f16x4 d4 = *(const f16x4*)&d2B[n2*S128 + rb];
        #pragma unroll
        for (int r=0;r<4;++r) acc3[ct][r] = (float)d4[r];
    }
    #pragma unroll
    for (int kk=0;kk<4;++kk){
        int ko = kk*32 + l4*8;
        f16x8 af = *(const f16x8*)&Alds[irow*S128 + ko];
        #pragma unroll
        for (int ct=0;ct<4;++ct){
            f16x8 bf = *(const f16x8*)&d2B[(ct*16+l15)*S128 + ko];
            acc3[ct] = MFMA16(af, bf, acc3[ct]);
        }
    }
    #pragma unroll
    for (int ct=0;ct<4;++ct){
        int n2 = ct*16+l15;
        #pragma unroll
        for (int r=0;r<4;++r) resid[(rb+r)*S72 + n2] = (f16)acc3[ct][r];
    }
    __syncthreads();

    // ---- G4: S/T = resid'@Ws + (rs+1)*cw + node@Ws_nd + bias; gated sum over nodes ----
    f32x4 aS[8], aT[8];
    #pragma unroll
    for (int ct=0;ct<8;++ct){
        int aux = ct*16+l15;
        float cwv = cw[aux], ctv = ctw[aux];
        float bsv = bs[aux], btv = bt[aux];
        #pragma unroll
        for (int r=0;r<4;++r){
            int n = rb + r;
            float rs1 = rsL[n] + 1.0f;
            float ns=0.f, nt=0.f;
            #pragma unroll
            for (int m=0;m<5;++m){
                float nv = node_l[n*5+m];
                ns += nv*Wsnd[m*128+aux];
                nt += nv*Wtnd[m*128+aux];
            }
            aS[ct][r] = bsv + rs1*cwv + ns;
            aT[ct][r] = btv + rs1*ctv + nt;
        }
    }
    #pragma unroll
    for (int kk=0;kk<2;++kk){
        int ko = kk*32 + l4*8;
        f16x8 af = *(const f16x8*)&resid[irow*S72 + ko];
        #pragma unroll
        for (int ct=0;ct<8;++ct){
            f16x8 bsf = *(const f16x8*)&WsB[(ct*16+l15)*S68 + ko];
            aS[ct] = MFMA16(af, bsf, aS[ct]);
            f16x8 btf = *(const f16x8*)&WtB[(ct*16+l15)*S68 + ko];
            aT[ct] = MFMA16(af, btf, aT[ct]);
        }
    }
    #pragma unroll
    for (int ct=0;ct<8;++ct){
        float v = 0.f;
        #pragma unroll
        for (int r=0;r<4;++r) v += sigm(aS[ct][r])*tanhf_(aT[ct][r]);
        v += __shfl_xor(v,16,64); v += __shfl_xor(v,32,64);
        if (lane<16) atomicAdd(&g_ac[ct*16+lane], v);
    }
    __syncthreads();

    // ---- head ----
    if (tid<128) g_ac[tid] = tanhf_(g_ac[tid]);
    __syncthreads();
    if (tid<128){
        float s = bl1[tid];
        for (int a2=0;a2<128;++a2) s += g_ac[a2]*Wl1[a2*128+tid];
        t1l[tid] = s;
    }
    __syncthreads();
    if (tid<64){
        float s = bl2[tid];
        for (int o=0;o<128;++o) s += t1l[o]*Wl2[o*64+tid];
        t2l[tid] = s;
        out[512 + bidx*64 + tid] = s;   // output 1: g [B,64]
    }
    __syncthreads();
    if (w==0){
        float v = t2l[lane]*Wo[lane];
        v += __shfl_xor(v,1,64);  v += __shfl_xor(v,2,64);
        v += __shfl_xor(v,4,64);  v += __shfl_xor(v,8,64);
        v += __shfl_xor(v,16,64); v += __shfl_xor(v,32,64);
        if (lane==0) out[bidx] = v + bo[0];   // output 0: out [B,1]
    }
}

extern "C" void kernel_launch(void* const* d_in, const int* in_sizes, int n_in,
                              void* d_out, int out_size, void* d_ws, size_t ws_size,
                              hipStream_t stream) {
    (void)in_sizes; (void)n_in; (void)out_size; (void)ws_size;
    const float* adj  = (const float*)d_in[0];
    const float* node = (const float*)d_in[1];
    const float* W1   = (const float*)d_in[2];
    const float* b1   = (const float*)d_in[3];
    const float* W2   = (const float*)d_in[4];
    const float* b2   = (const float*)d_in[5];
    const float* Ws   = (const float*)d_in[6];
    const float* bs   = (const float*)d_in[7];
    const float* Wt   = (const float*)d_in[8];
    const float* bt   = (const float*)d_in[9];
    const float* Wl1  = (const float*)d_in[10];
    const float* bl1  = (const float*)d_in[11];
    const float* Wl2  = (const float*)d_in[12];
    const float* bl2  = (const float*)d_in[13];
    const float* Wo   = (const float*)d_in[14];
    const float* bo   = (const float*)d_in[15];
    f16*   Ag  = (f16*)d_ws;                               // 16.78 MB fp16 centered adjacency
    float* rsG = (float*)((char*)d_ws + 33554432/2 + 0);   // fp32 rowsums after Ag
    rsG = (float*)((char*)d_ws + 16777216);

    k_buildA<<<dim3(8192), dim3(256), 0, stream>>>(adj, Ag, rsG);
    k_main<<<dim3(512), dim3(512), 0, stream>>>(Ag, rsG, node, W1,b1,W2,b2,Ws,bs,Wt,bt,
                                                Wl1,bl1,Wl2,bl2,Wo,bo, (float*)d_out);
}

// Round 3
// 97.388 us; speedup vs baseline: 1.0094x; 1.0094x over previous
//
#include <hip/hip_runtime.h>

typedef _Float16 f16;
typedef _Float16 f16x8 __attribute__((ext_vector_type(8)));
typedef _Float16 f16x4 __attribute__((ext_vector_type(4)));
typedef float f32x4 __attribute__((ext_vector_type(4)));

#define MFMA16(a,b,c) __builtin_amdgcn_mfma_f32_16x16x32_f16((a),(b),(c),0,0,0)

__device__ __forceinline__ float sigm(float x){ return 1.0f/(1.0f+__expf(-x)); }
__device__ __forceinline__ float tanhf_(float x){ return 1.0f - 2.0f/(1.0f+__expf(2.0f*x)); }

// One block per batch element. Streams raw adj (coalesced, double-buffered),
// builds Ac = A-2 (fp16) + exact fp32 rowsums in LDS, then runs the whole
// chain: h1 -> G1 -> G2 -> G3 -> G4 -> head. Rank-1/mean parts in fp32.
#define S128 136
#define S68  68
#define S72  72

__global__ __launch_bounds__(512,2) void k_main(
    const float* __restrict__ adj,
    const float* __restrict__ node_g,
    const float* __restrict__ W1,  const float* __restrict__ b1,
    const float* __restrict__ W2,  const float* __restrict__ b2,
    const float* __restrict__ Ws,  const float* __restrict__ bs,
    const float* __restrict__ Wt,  const float* __restrict__ bt,
    const float* __restrict__ Wl1, const float* __restrict__ bl1,
    const float* __restrict__ Wl2, const float* __restrict__ bl2,
    const float* __restrict__ Wo,  const float* __restrict__ bo,
    float* __restrict__ out)
{
    __shared__ __align__(16) char smem[136960];
    f16*   Alds  = (f16*)(smem);               // [128][136]  Ac = A-2 (fp16)
    float* stg0  = (float*)(smem+34816);       // [10240] staging chunk buf 0 (16 rows)
    float* stg1  = (float*)(smem+75776);       // [10240] staging chunk buf 1
    f16*   h1B   = (f16*)(smem+34816);         // [128][136]  h1^T [c][n]   (after staging)
    f16*   W2B   = (f16*)(smem+34816);         // [64][136]   (after G1)
    f16*   resid = (f16*)(smem+34816);         // [128][72]   resid'=Ac@d2+d2 (after G2)
    f16*   h_d   = (f16*)(smem+69632);         // [128][136]  h - mean_j(h), [j][c]
    f16*   WsB   = (f16*)(smem+69632);         // [128][68]   (after G2)
    f16*   WtB   = (f16*)(smem+87040);         // [128][68]
    f16*   d2B   = (f16*)(smem+104448);        // [64][136]   h2 - c, B-layout [n2][j]
    float* node_l= (float*)(smem+121856);      // [640]
    float* W1L   = (float*)(smem+124416);      // [640]
    float* Wsnd  = (float*)(smem+126976);      // [640] Ws rows 64..68
    float* Wtnd  = (float*)(smem+129536);      // [640]
    float* b1L   = (float*)(smem+132096);      // [128]
    float* sum1  = (float*)(smem+132608);      // [128] sum_n h1f32[n][c]
    float* m_h   = (float*)(smem+133120);      // [128]
    float* rsL   = (float*)(smem+133632);      // [128] exact fp32 rowsum(A)
    float* c_ac  = (float*)(smem+134144);      // [64]
    float* cw    = (float*)(smem+134400);      // [128] c@Ws fp32
    float* ctw   = (float*)(smem+134912);      // [128]
    float* g_ac  = (float*)(smem+135424);      // [128]
    float* r1_2  = (float*)(smem+135936);      // [64]  m_h@W2+b2 fp32
    float* t1l   = (float*)(smem+136192);      // [128]
    float* t2l   = (float*)(smem+136704);      // [64]

    const int bidx = blockIdx.x;
    const int tid  = threadIdx.x;
    const int w    = tid>>6, lane = tid&63;
    const int l15  = lane&15, l4 = lane>>4;
    const int irow = w*16 + l15;         // A-operand row for this wave
    const int rb   = w*16 + l4*4;        // C/D row base

    // ---- phase 0: zero + stage small arrays (no cross-thread reads yet) ----
    if (tid<128){ m_h[tid]=0.f; g_ac[tid]=0.f; sum1[tid]=0.f; b1L[tid]=b1[tid]; }
    if (tid<64)  c_ac[tid]=0.f;
    for (int i=tid;i<640;i+=512){
        node_l[i] = node_g[bidx*640+i];
        W1L[i]    = W1[i];
        Wsnd[i]   = Ws[64*128+i];
        Wtnd[i]   = Wt[64*128+i];
    }

    // ---- stream adj -> Ac(LDS,fp16) + rowsums, 8 chunks x 16 rows, dbuf ----
    {
        const float4* asrc = (const float4*)(adj + (long long)bidx*81920);
        float4 pre[5];
        #pragma unroll
        for (int k=0;k<5;++k) pre[k] = asrc[k*512 + tid];
        {
            float4* dst = (float4*)stg0;
            #pragma unroll
            for (int k=0;k<5;++k) dst[k*512+tid] = pre[k];
        }
        __syncthreads();
        for (int c=0; c<8; ++c){
            if (c+1<8){ // issue next-chunk loads early (hide HBM latency)
                #pragma unroll
                for (int k=0;k<5;++k) pre[k] = asrc[(c+1)*2560 + k*512 + tid];
            }
            // consume current buffer: this thread owns 20 consecutive floats
            const float* sb = (c&1)? stg1 : stg0;
            float4 v0 = *(const float4*)&sb[20*tid];
            float4 v1 = *(const float4*)&sb[20*tid+4];
            float4 v2 = *(const float4*)&sb[20*tid+8];
            float4 v3 = *(const float4*)&sb[20*tid+12];
            float4 v4 = *(const float4*)&sb[20*tid+16];
            float s0 = v0.y + v0.z + v0.w + v1.x;
            float s1 = v1.z + v1.w + v2.x + v2.y;
            float s2 = v2.w + v3.x + v3.y + v3.z;
            float s3 = v4.x + v4.y + v4.z + v4.w;
            int r  = c*16 + (tid>>5);
            int j0 = (tid&31)*4;
            f16x4 o; o[0]=(f16)(s0-2.0f); o[1]=(f16)(s1-2.0f);
                     o[2]=(f16)(s2-2.0f); o[3]=(f16)(s3-2.0f);
            *(f16x4*)&Alds[r*S128 + j0] = o;
            // exact fp32 rowsum: 32 consecutive lanes own one row
            float v = s0+s1+s2+s3;
            v += __shfl_xor(v, 1, 64); v += __shfl_xor(v, 2, 64);
            v += __shfl_xor(v, 4, 64); v += __shfl_xor(v, 8, 64);
            v += __shfl_xor(v,16, 64);
            if ((lane&31)==0) rsL[r] = v;
            if (c+1<8){ // write prefetched chunk to the other buffer
                float4* dst = ((c+1)&1)? (float4*)stg1 : (float4*)stg0;
                #pragma unroll
                for (int k=0;k<5;++k) dst[k*512+tid] = pre[k];
            }
            __syncthreads();
        }
    }

    { // h1 = node@W1 + b1 (fp32), stored fp16 B-layout [c][n]; fp32 column sums
        int c = tid>>2, nq = (tid&3)*32;
        float w1v[5]; float bb = b1L[c];
        #pragma unroll
        for (int m=0;m<5;++m) w1v[m] = W1L[m*128+c];
        float part = 0.f;
        for (int n=nq; n<nq+32; ++n){
            float a = bb;
            #pragma unroll
            for (int m=0;m<5;++m) a += node_l[n*5+m]*w1v[m];
            h1B[c*S128+n] = (f16)a;
            part += a;
        }
        atomicAdd(&sum1[c], part);
    }
    __syncthreads();

    // ---- G1: h = A@h1 + h1 = Ac@h1 + 2*sum1[c] + h1  (init in exact fp32) ----
    f32x4 acc[8];
    #pragma unroll
    for (int ct=0;ct<8;++ct){
        int c = ct*16+l15;
        float s2c = 2.0f*sum1[c], bb = b1L[c];
        #pragma unroll
        for (int r=0;r<4;++r){
            int n = rb+r;
            float a = bb;
            #pragma unroll
            for (int m=0;m<5;++m) a += node_l[n*5+m]*W1L[m*128+c];
            acc[ct][r] = a + s2c;
        }
    }
    #pragma unroll
    for (int kk=0;kk<4;++kk){
        int ko = kk*32 + l4*8;
        f16x8 af = *(const f16x8*)&Alds[irow*S128 + ko];
        #pragma unroll
        for (int ct=0;ct<8;++ct){
            f16x8 bf = *(const f16x8*)&h1B[(ct*16+l15)*S128 + ko];
            acc[ct] = MFMA16(af, bf, acc[ct]);
        }
    }
    // column means of h (exact mean of OUR h)
    #pragma unroll
    for (int ct=0;ct<8;++ct){
        float v = acc[ct][0]+acc[ct][1]+acc[ct][2]+acc[ct][3];
        v += __shfl_xor(v,16,64); v += __shfl_xor(v,32,64);
        if (lane<16) atomicAdd(&m_h[ct*16+lane], v);
    }
    __syncthreads();
    if (tid<128) m_h[tid] *= (1.0f/128.0f);
    { // stage W2^T -> fp16 (overwrites dead h1B)
        int n2 = tid>>3, c0 = (tid&7)*16;
        #pragma unroll
        for (int cc=0; cc<16; ++cc)
            W2B[n2*S128 + c0+cc] = (f16)W2[(c0+cc)*64 + n2];
    }
    __syncthreads();
    #pragma unroll
    for (int ct=0;ct<8;++ct){ // h_d = h - mean (A-layout [j][c])
        int c = ct*16+l15; float mh = m_h[c];
        #pragma unroll
        for (int r=0;r<4;++r) h_d[(rb+r)*S128 + c] = (f16)(acc[ct][r]-mh);
    }
    if (tid<64){ // rank-1: mean_h @ W2 + b2 in fp32
        float s = b2[tid];
        for (int c=0;c<128;++c) s += m_h[c]*W2[c*64+tid];
        r1_2[tid] = s;
    }
    __syncthreads();

    // ---- G2: h2 = h_d@W2 + (mean_h@W2+b2) ----
    f32x4 acc2[4];
    #pragma unroll
    for (int ct=0;ct<4;++ct){
        float rv = r1_2[ct*16+l15];
        acc2[ct][0]=rv; acc2[ct][1]=rv; acc2[ct][2]=rv; acc2[ct][3]=rv;
    }
    #pragma unroll
    for (int kk=0;kk<4;++kk){
        int ko = kk*32 + l4*8;
        f16x8 af = *(const f16x8*)&h_d[irow*S128 + ko];
        #pragma unroll
        for (int ct=0;ct<4;++ct){
            f16x8 bf = *(const f16x8*)&W2B[(ct*16+l15)*S128 + ko];
            acc2[ct] = MFMA16(af, bf, acc2[ct]);
        }
    }
    #pragma unroll
    for (int ct=0;ct<4;++ct){
        float v = acc2[ct][0]+acc2[ct][1]+acc2[ct][2]+acc2[ct][3];
        v += __shfl_xor(v,16,64); v += __shfl_xor(v,32,64);
        if (lane<16) atomicAdd(&c_ac[ct*16+lane], v);
    }
    __syncthreads();
    if (tid<64) c_ac[tid] *= (1.0f/128.0f);
    __syncthreads();
    #pragma unroll
    for (int ct=0;ct<4;++ct){ // d2 = h2 - c, B-layout [n2][j]
        int n2 = ct*16+l15; float cv = c_ac[n2];
        f16x4 pk;
        #pragma unroll
        for (int r=0;r<4;++r) pk[r] = (f16)(acc2[ct][r]-cv);
        *(f16x4*)&d2B[n2*S128 + rb] = pk;
    }
    if (tid<256){ // cw/ctw = c @ Ws/Wt (fp32 exact rank-1 path)
        int aux = tid&127; const float* Wx = (tid<128)? Ws : Wt;
        float s=0.f;
        for (int n2=0;n2<64;++n2) s += c_ac[n2]*Wx[n2*128+aux];
        ((tid<128)? cw : ctw)[aux] = s;
    }
    { // stage Ws^T/Wt^T rows 0..63 -> fp16 (overwrites dead h_d)
        int aux = tid>>2, q = tid&3;
        #pragma unroll
        for (int k=0;k<16;++k){
            int n2 = q*16+k;
            WsB[aux*S68+n2] = (f16)Ws[n2*128+aux];
            WtB[aux*S68+n2] = (f16)Wt[n2*128+aux];
        }
    }
    __syncthreads();

    // ---- G3: resid' = Ac@d2 + d2   (hb = resid' + (rs+1)*c; sum_j d2 = 0 exactly) ----
    f32x4 acc3[4];
    #pragma unroll
    for (int ct=0;ct<4;++ct){
        int n2 = ct*16+l15;
        f16x4 d4 = *(const f16x4*)&d2B[n2*S128 + rb];
        #pragma unroll
        for (int r=0;r<4;++r) acc3[ct][r] = (float)d4[r];
    }
    #pragma unroll
    for (int kk=0;kk<4;++kk){
        int ko = kk*32 + l4*8;
        f16x8 af = *(const f16x8*)&Alds[irow*S128 + ko];
        #pragma unroll
        for (int ct=0;ct<4;++ct){
            f16x8 bf = *(const f16x8*)&d2B[(ct*16+l15)*S128 + ko];
            acc3[ct] = MFMA16(af, bf, acc3[ct]);
        }
    }
    #pragma unroll
    for (int ct=0;ct<4;++ct){
        int n2 = ct*16+l15;
        #pragma unroll
        for (int r=0;r<4;++r) resid[(rb+r)*S72 + n2] = (f16)acc3[ct][r];
    }
    __syncthreads();

    // ---- G4: S/T = resid'@Ws + (rs+1)*cw + node@Ws_nd + bias; gated sum ----
    f32x4 aS[8], aT[8];
    #pragma unroll
    for (int ct=0;ct<8;++ct){
        int aux = ct*16+l15;
        float cwv = cw[aux], ctv = ctw[aux];
        float bsv = bs[aux], btv = bt[aux];
        #pragma unroll
        for (int r=0;r<4;++r){
            int n = rb + r;
            float rs1 = rsL[n] + 1.0f;
            float ns=0.f, nt=0.f;
            #pragma unroll
            for (int m=0;m<5;++m){
                float nv = node_l[n*5+m];
                ns += nv*Wsnd[m*128+aux];
                nt += nv*Wtnd[m*128+aux];
            }
            aS[ct][r] = bsv + rs1*cwv + ns;
            aT[ct][r] = btv + rs1*ctv + nt;
        }
    }
    #pragma unroll
    for (int kk=0;kk<2;++kk){
        int ko = kk*32 + l4*8;
        f16x8 af = *(const f16x8*)&resid[irow*S72 + ko];
        #pragma unroll
        for (int ct=0;ct<8;++ct){
            f16x8 bsf = *(const f16x8*)&WsB[(ct*16+l15)*S68 + ko];
            aS[ct] = MFMA16(af, bsf, aS[ct]);
            f16x8 btf = *(const f16x8*)&WtB[(ct*16+l15)*S68 + ko];
            aT[ct] = MFMA16(af, btf, aT[ct]);
        }
    }
    #pragma unroll
    for (int ct=0;ct<8;++ct){
        float v = 0.f;
        #pragma unroll
        for (int r=0;r<4;++r) v += sigm(aS[ct][r])*tanhf_(aT[ct][r]);
        v += __shfl_xor(v,16,64); v += __shfl_xor(v,32,64);
        if (lane<16) atomicAdd(&g_ac[ct*16+lane], v);
    }
    __syncthreads();

    // ---- head ----
    if (tid<128) g_ac[tid] = tanhf_(g_ac[tid]);
    __syncthreads();
    if (tid<128){
        float s = bl1[tid];
        for (int a2=0;a2<128;++a2) s += g_ac[a2]*Wl1[a2*128+tid];
        t1l[tid] = s;
    }
    __syncthreads();
    if (tid<64){
        float s = bl2[tid];
        for (int o=0;o<128;++o) s += t1l[o]*Wl2[o*64+tid];
        t2l[tid] = s;
        out[512 + bidx*64 + tid] = s;   // output 1: g [B,64]
    }
    __syncthreads();
    if (w==0){
        float v = t2l[lane]*Wo[lane];
        v += __shfl_xor(v,1,64);  v += __shfl_xor(v,2,64);
        v += __shfl_xor(v,4,64);  v += __shfl_xor(v,8,64);
        v += __shfl_xor(v,16,64); v += __shfl_xor(v,32,64);
        if (lane==0) out[bidx] = v + bo[0];   // output 0: out [B,1]
    }
}

extern "C" void kernel_launch(void* const* d_in, const int* in_sizes, int n_in,
                              void* d_out, int out_size, void* d_ws, size_t ws_size,
                              hipStream_t stream) {
    (void)in_sizes; (void)n_in; (void)out_size; (void)d_ws; (void)ws_size;
    const float* adj  = (const float*)d_in[0];
    const float* node = (const float*)d_in[1];
    const float* W1   = (const float*)d_in[2];
    const float* b1   = (const float*)d_in[3];
    const float* W2   = (const float*)d_in[4];
    const float* b2   = (const float*)d_in[5];
    const float* Ws   = (const float*)d_in[6];
    const float* bs   = (const float*)d_in[7];
    const float* Wt   = (const float*)d_in[8];
    const float* bt   = (const float*)d_in[9];
    const float* Wl1  = (const float*)d_in[10];
    const float* bl1  = (const float*)d_in[11];
    const float* Wl2  = (const float*)d_in[12];
    const float* bl2  = (const float*)d_in[13];
    const float* Wo   = (const float*)d_in[14];
    const float* bo   = (const float*)d_in[15];

    k_main<<<dim3(512), dim3(512), 0, stream>>>(adj, node, W1,b1,W2,b2,Ws,bs,Wt,bt,
                                                Wl1,bl1,Wl2,bl2,Wo,bo, (float*)d_out);
}